// Round 1
// baseline (515.522 us; speedup 1.0000x reference)
//
#include <hip/hip_runtime.h>

#define CIN  64
#define COUT 64
#define KVOL 27
#define ROWS_PER_WAVE 32
#define WAVES_PER_BLOCK 4

__global__ __launch_bounds__(256) void spconv_gather_fp32(
    const float* __restrict__ feats,
    const float* __restrict__ weight,
    const float* __restrict__ bias,
    const int*   __restrict__ in_idx,
    const float* __restrict__ mask,
    float* __restrict__ out,
    int n)
{
    const int lane = threadIdx.x & 63;
    const int wave_in_block = threadIdx.x >> 6;
    const int wave = blockIdx.x * WAVES_PER_BLOCK + wave_in_block;
    const int row0 = wave * ROWS_PER_WAVE;
    if (row0 >= n) return;

    // accumulators: one output row per register, lane = c_out
    float acc[ROWS_PER_WAVE];
    const float b = bias[lane];
    #pragma unroll
    for (int r = 0; r < ROWS_PER_WAVE; ++r) acc[r] = b;

    for (int k = 0; k < KVOL; ++k) {
        // stage this offset's weight column for my c_out into VGPRs
        // w[c] = weight[k][c][lane]; lanes consecutive -> coalesced 256B loads
        float w[CIN];
        const float* wk = weight + (size_t)k * CIN * COUT + lane;
        #pragma unroll
        for (int c = 0; c < CIN; ++c) w[c] = wk[c * COUT];

        const int*   ii = in_idx + (size_t)k * n;
        const float* mm = mask   + (size_t)k * n;

        #pragma unroll
        for (int r = 0; r < ROWS_PER_WAVE; ++r) {
            const int row = row0 + r;
            const float m = mm[row];          // wave-uniform
            if (m != 0.0f) {                  // uniform branch: whole wave skips
                // wave-uniform gather row -> force scalar (s_load) path
                const int ir = __builtin_amdgcn_readfirstlane(ii[row]);
                const float* frow = feats + (size_t)ir * CIN;
                #pragma unroll
                for (int c = 0; c < CIN; ++c)
                    acc[r] = fmaf(frow[c], w[c], acc[r]);
            }
        }
    }

    // coalesced store: out[row][lane]
    float* orow = out + (size_t)row0 * COUT + lane;
    #pragma unroll
    for (int r = 0; r < ROWS_PER_WAVE; ++r)
        orow[(size_t)r * COUT] = acc[r];
}

extern "C" void kernel_launch(void* const* d_in, const int* in_sizes, int n_in,
                              void* d_out, int out_size, void* d_ws, size_t ws_size,
                              hipStream_t stream)
{
    const float* feats  = (const float*)d_in[0];
    const float* weight = (const float*)d_in[1];
    const float* bias   = (const float*)d_in[2];
    const int*   in_idx = (const int*)  d_in[3];
    // d_in[4] = out_idx (unused: out_idx[k][i] == i where mask==1)
    const float* mask   = (const float*)d_in[5];
    float* out = (float*)d_out;

    const int n = in_sizes[0] / CIN;  // 262144

    const int rows_per_block = ROWS_PER_WAVE * WAVES_PER_BLOCK;  // 128
    const int grid = (n + rows_per_block - 1) / rows_per_block;

    spconv_gather_fp32<<<grid, 256, 0, stream>>>(feats, weight, bias,
                                                 in_idx, mask, out, n);
}

// Round 2
// 142.876 us; speedup vs baseline: 3.6082x; 3.6082x over previous
//
#include <hip/hip_runtime.h>

#define CIN  64
#define COUT 64
#define KVOL 27

typedef __attribute__((ext_vector_type(8))) short bf16x8;
typedef __attribute__((ext_vector_type(4))) float f32x4;

union U4H8 { uint4 u; bf16x8 h; };

static __device__ __forceinline__ unsigned short f2bf(float x) {
    union { float f; unsigned int u; } v; v.f = x;
    return (unsigned short)((v.u + 0x7FFFu + ((v.u >> 16) & 1u)) >> 16);  // RNE
}

// Re-pack weight[27][64][64] fp32 -> bf16 B-fragment order:
// entry e = (k*8 + frag)*64 + lane holds 8 bf16 = W[k][32*kh + (lane>>4)*8 + j][16*nt + (lane&15)]
// where frag = kh*4 + nt.  One thread per entry (27*8*64 = 13824).
__global__ __launch_bounds__(256) void pack_w(const float* __restrict__ W,
                                              unsigned short* __restrict__ wf) {
    int t = blockIdx.x * 256 + threadIdx.x;
    if (t >= KVOL * 8 * 64) return;
    int lane  = t & 63;
    int frag  = (t >> 6) & 7;
    int k     = t >> 9;
    int kh    = frag >> 2, nt = frag & 3;
    int col   = nt * 16 + (lane & 15);
    int kbase = kh * 32 + (lane >> 4) * 8;
    const float* src = W + (size_t)k * (CIN * COUT) + (size_t)kbase * COUT + col;
    unsigned int pk[4];
    #pragma unroll
    for (int j = 0; j < 4; ++j) {
        unsigned int lo = f2bf(src[(2 * j) * COUT]);
        unsigned int hi = f2bf(src[(2 * j + 1) * COUT]);
        pk[j] = lo | (hi << 16);
    }
    *reinterpret_cast<uint4*>(wf + (size_t)t * 8) = make_uint4(pk[0], pk[1], pk[2], pk[3]);
}

static __device__ __forceinline__ bf16x8 cvt8(float4 a, float4 b, float m) {
    bf16x8 r;
    r[0] = (short)f2bf(a.x * m); r[1] = (short)f2bf(a.y * m);
    r[2] = (short)f2bf(a.z * m); r[3] = (short)f2bf(a.w * m);
    r[4] = (short)f2bf(b.x * m); r[5] = (short)f2bf(b.y * m);
    r[6] = (short)f2bf(b.z * m); r[7] = (short)f2bf(b.w * m);
    return r;
}

// Block = 256 threads = 4 waves, 128 output rows/block (32 rows/wave as 2 M-tiles).
// Dense per-k compute: invalid pairs gather feats[0] (L1-hot) * mask 0.
__global__ __launch_bounds__(256) void spconv_mfma(
    const float* __restrict__ feats,
    const unsigned short* __restrict__ wf,
    const float* __restrict__ bias,
    const int*   __restrict__ in_idx,
    const float* __restrict__ mask,
    float* __restrict__ out, int n)
{
    const int tid  = threadIdx.x;
    const int lane = tid & 63;
    const int wv   = tid >> 6;
    const int rloc = lane & 15;
    const int grp  = lane >> 4;
    const int row0 = blockIdx.x * 128 + wv * 32;

    __shared__ uint4 lds_w[2][512];   // double-buffered B-fragments, 16 KB

    f32x4 acc[2][4];
    #pragma unroll
    for (int nt = 0; nt < 4; ++nt) {
        float b = bias[nt * 16 + rloc];
        f32x4 v = {b, b, b, b};
        acc[0][nt] = v; acc[1][nt] = v;
    }

    const uint4* wf4 = reinterpret_cast<const uint4*>(wf);

    // stage k=0
    lds_w[0][2 * tid]     = wf4[2 * tid];
    lds_w[0][2 * tid + 1] = wf4[2 * tid + 1];
    __syncthreads();

    const int rowA = row0 + rloc;
    const int rowB = rowA + 16;

    for (int koff = 0; koff < KVOL; ++koff) {
        const int cur = koff & 1;
        if (koff + 1 < KVOL) {                       // prefetch next weight tile
            const uint4* s = wf4 + (size_t)(koff + 1) * 512;
            lds_w[cur ^ 1][2 * tid]     = s[2 * tid];
            lds_w[cur ^ 1][2 * tid + 1] = s[2 * tid + 1];
        }

        const size_t kb = (size_t)koff * n;
        const int   idxA = in_idx[kb + rowA];
        const float mA   = mask[kb + rowA];
        const int   idxB = in_idx[kb + rowB];
        const float mB   = mask[kb + rowB];

        // A gather: lane covers k-chunk grp*8..grp*8+7 (kh0) and +32 (kh1)
        const float4* fA = reinterpret_cast<const float4*>(feats + (size_t)idxA * CIN + grp * 8);
        const float4* fB = reinterpret_cast<const float4*>(feats + (size_t)idxB * CIN + grp * 8);
        float4 a0 = fA[0], a1 = fA[1], a2 = fA[8], a3 = fA[9];
        float4 c0 = fB[0], c1 = fB[1], c2 = fB[8], c3 = fB[9];

        bf16x8 aA0 = cvt8(a0, a1, mA), aA1 = cvt8(a2, a3, mA);
        bf16x8 aB0 = cvt8(c0, c1, mB), aB1 = cvt8(c2, c3, mB);

        U4H8 bf[2][4];
        #pragma unroll
        for (int kh = 0; kh < 2; ++kh)
            #pragma unroll
            for (int nt = 0; nt < 4; ++nt)
                bf[kh][nt].u = lds_w[cur][(kh * 4 + nt) * 64 + lane];

        #pragma unroll
        for (int nt = 0; nt < 4; ++nt) {
            acc[0][nt] = __builtin_amdgcn_mfma_f32_16x16x32_bf16(aA0, bf[0][nt].h, acc[0][nt], 0, 0, 0);
            acc[0][nt] = __builtin_amdgcn_mfma_f32_16x16x32_bf16(aA1, bf[1][nt].h, acc[0][nt], 0, 0, 0);
            acc[1][nt] = __builtin_amdgcn_mfma_f32_16x16x32_bf16(aB0, bf[0][nt].h, acc[1][nt], 0, 0, 0);
            acc[1][nt] = __builtin_amdgcn_mfma_f32_16x16x32_bf16(aB1, bf[1][nt].h, acc[1][nt], 0, 0, 0);
        }
        __syncthreads();
    }

    // C/D layout (HW-verified): col = lane&15, row = grp*4 + reg
    #pragma unroll
    for (int t = 0; t < 2; ++t)
        #pragma unroll
        for (int nt = 0; nt < 4; ++nt)
            #pragma unroll
            for (int r = 0; r < 4; ++r) {
                int orow = row0 + t * 16 + grp * 4 + r;
                out[(size_t)orow * COUT + nt * 16 + rloc] = acc[t][nt][r];
            }
}

extern "C" void kernel_launch(void* const* d_in, const int* in_sizes, int n_in,
                              void* d_out, int out_size, void* d_ws, size_t ws_size,
                              hipStream_t stream)
{
    const float* feats  = (const float*)d_in[0];
    const float* weight = (const float*)d_in[1];
    const float* bias   = (const float*)d_in[2];
    const int*   in_idx = (const int*)  d_in[3];
    // d_in[4] = out_idx (unused: out_idx[k][i] == i where mask==1)
    const float* mask   = (const float*)d_in[5];
    float* out = (float*)d_out;

    const int n = in_sizes[0] / CIN;  // 262144

    unsigned short* wf = (unsigned short*)d_ws;  // needs 27*8*64*16 B = 221 KB
    const int packN = KVOL * 8 * 64;
    pack_w<<<(packN + 255) / 256, 256, 0, stream>>>(weight, wf);

    spconv_mfma<<<n / 128, 256, 0, stream>>>(feats, wf, bias, in_idx, mask, out, n);
}

// Round 3
// 111.826 us; speedup vs baseline: 4.6100x; 1.2777x over previous
//
#include <hip/hip_runtime.h>

#define CIN  64
#define COUT 64
#define KVOL 27

typedef __attribute__((ext_vector_type(8))) short bf16x8;
typedef __attribute__((ext_vector_type(4))) float f32x4;

union U4H8 { uint4 u; bf16x8 h; };

static __device__ __forceinline__ unsigned short f2bf(float x) {
    union { float f; unsigned int u; } v; v.f = x;
    return (unsigned short)((v.u + 0x7FFFu + ((v.u >> 16) & 1u)) >> 16);  // RNE
}

// Re-pack weight[27][64][64] fp32 -> bf16 B-fragment order:
// entry e = (k*8 + frag)*64 + lane holds 8 bf16 = W[k][32*kh + (lane>>4)*8 + j][16*nt + (lane&15)]
__global__ __launch_bounds__(256) void pack_w(const float* __restrict__ W,
                                              unsigned short* __restrict__ wf) {
    int t = blockIdx.x * 256 + threadIdx.x;
    if (t >= KVOL * 8 * 64) return;
    int lane  = t & 63;
    int frag  = (t >> 6) & 7;
    int k     = t >> 9;
    int kh    = frag >> 2, nt = frag & 3;
    int col   = nt * 16 + (lane & 15);
    int kbase = kh * 32 + (lane >> 4) * 8;
    const float* src = W + (size_t)k * (CIN * COUT) + (size_t)kbase * COUT + col;
    unsigned int pk[4];
    #pragma unroll
    for (int j = 0; j < 4; ++j) {
        unsigned int lo = f2bf(src[(2 * j) * COUT]);
        unsigned int hi = f2bf(src[(2 * j + 1) * COUT]);
        pk[j] = lo | (hi << 16);
    }
    *reinterpret_cast<uint4*>(wf + (size_t)t * 8) = make_uint4(pk[0], pk[1], pk[2], pk[3]);
}

// feats fp32 [N][64] -> bf16 [N+1][64] (row N = zeros). One thread = 8 elems.
__global__ __launch_bounds__(256) void cvt_feats(const float* __restrict__ f,
                                                 uint4* __restrict__ o, int total8) {
    int t = blockIdx.x * 256 + threadIdx.x;
    if (t < total8) {
        const float4* p = reinterpret_cast<const float4*>(f) + 2 * (size_t)t;
        float4 a = p[0], b = p[1];
        unsigned int u0 = (unsigned int)f2bf(a.x) | ((unsigned int)f2bf(a.y) << 16);
        unsigned int u1 = (unsigned int)f2bf(a.z) | ((unsigned int)f2bf(a.w) << 16);
        unsigned int u2 = (unsigned int)f2bf(b.x) | ((unsigned int)f2bf(b.y) << 16);
        unsigned int u3 = (unsigned int)f2bf(b.z) | ((unsigned int)f2bf(b.w) << 16);
        o[t] = make_uint4(u0, u1, u2, u3);
    } else if (t < total8 + 8) {
        o[t] = make_uint4(0u, 0u, 0u, 0u);   // zero row at index N
    }
}

// Main: 4 waves/block, 128 rows/block (32 rows/wave = 2 M-tiles of 16).
// Dense per-k: invalid pairs gather the zero row (exact zeros, no mask mul).
__global__ __launch_bounds__(256) void spconv_mfma_bf16(
    const char* __restrict__ fbf,          // (n+1) rows x 128 B
    const uint4* __restrict__ wf4,
    const float* __restrict__ bias,
    const int*   __restrict__ in_idx,
    const float* __restrict__ mask,
    float* __restrict__ out, int n)
{
    const int tid  = threadIdx.x;
    const int lane = tid & 63;
    const int wv   = tid >> 6;
    const int rloc = lane & 15;
    const int grp  = lane >> 4;
    const int row0 = blockIdx.x * 128 + wv * 32;

    __shared__ uint4 lds_w[2][512];        // double-buffered B-fragments, 16 KB

    f32x4 acc[2][4];
    #pragma unroll
    for (int nt = 0; nt < 4; ++nt) {
        float b = bias[nt * 16 + rloc];
        f32x4 v = {b, b, b, b};
        acc[0][nt] = v; acc[1][nt] = v;
    }

    // stage k=0 (conflict-free: linear thread->entry)
    lds_w[0][tid]       = wf4[tid];
    lds_w[0][tid + 256] = wf4[tid + 256];
    __syncthreads();

    const int rowA = row0 + rloc;
    const int rowB = rowA + 16;
    const unsigned int zoff = (unsigned int)n * 128u;

    for (int koff = 0; koff < KVOL; ++koff) {
        const int cur = koff & 1;

        // T14: issue next-k weight loads early (write to LDS after MFMA)
        uint4 w0, w1;
        const bool pf = (koff + 1 < KVOL);
        if (pf) {
            const uint4* s = wf4 + (size_t)(koff + 1) * 512;
            w0 = s[tid];
            w1 = s[tid + 256];
        }

        const size_t kb = (size_t)koff * n;
        const int   idxA = in_idx[kb + rowA];
        const float mA   = mask[kb + rowA];
        const int   idxB = in_idx[kb + rowB];
        const float mB   = mask[kb + rowB];

        const unsigned int offA = (mA != 0.0f) ? (unsigned int)idxA * 128u : zoff;
        const unsigned int offB = (mB != 0.0f) ? (unsigned int)idxB * 128u : zoff;

        // A gather: lane covers bf16 k-chunk grp*8..+7 (kh0) and +32 (kh1)
        const uint4* pA = reinterpret_cast<const uint4*>(fbf + offA + grp * 16);
        const uint4* pB = reinterpret_cast<const uint4*>(fbf + offB + grp * 16);
        U4H8 aA0, aA1, aB0, aB1;
        aA0.u = pA[0]; aA1.u = pA[4];
        aB0.u = pB[0]; aB1.u = pB[4];

        U4H8 bf[2][4];
        #pragma unroll
        for (int kh = 0; kh < 2; ++kh)
            #pragma unroll
            for (int nt = 0; nt < 4; ++nt)
                bf[kh][nt].u = lds_w[cur][(kh * 4 + nt) * 64 + lane];

        #pragma unroll
        for (int nt = 0; nt < 4; ++nt) {
            acc[0][nt] = __builtin_amdgcn_mfma_f32_16x16x32_bf16(aA0.h, bf[0][nt].h, acc[0][nt], 0, 0, 0);
            acc[0][nt] = __builtin_amdgcn_mfma_f32_16x16x32_bf16(aA1.h, bf[1][nt].h, acc[0][nt], 0, 0, 0);
            acc[1][nt] = __builtin_amdgcn_mfma_f32_16x16x32_bf16(aB0.h, bf[0][nt].h, acc[1][nt], 0, 0, 0);
            acc[1][nt] = __builtin_amdgcn_mfma_f32_16x16x32_bf16(aB1.h, bf[1][nt].h, acc[1][nt], 0, 0, 0);
        }

        if (pf) {
            lds_w[cur ^ 1][tid]       = w0;
            lds_w[cur ^ 1][tid + 256] = w1;
        }
        __syncthreads();
    }

    // C/D layout: col = lane&15, row = grp*4 + reg
    #pragma unroll
    for (int t = 0; t < 2; ++t)
        #pragma unroll
        for (int nt = 0; nt < 4; ++nt)
            #pragma unroll
            for (int r = 0; r < 4; ++r) {
                int orow = row0 + t * 16 + grp * 4 + r;
                out[(size_t)orow * COUT + nt * 16 + rloc] = acc[t][nt][r];
            }
}

// ---- fallback (round-2 kernel): fp32 gather + in-loop cvt, used if ws too small ----
static __device__ __forceinline__ bf16x8 cvt8(float4 a, float4 b, float m) {
    bf16x8 r;
    r[0] = (short)f2bf(a.x * m); r[1] = (short)f2bf(a.y * m);
    r[2] = (short)f2bf(a.z * m); r[3] = (short)f2bf(a.w * m);
    r[4] = (short)f2bf(b.x * m); r[5] = (short)f2bf(b.y * m);
    r[6] = (short)f2bf(b.z * m); r[7] = (short)f2bf(b.w * m);
    return r;
}

__global__ __launch_bounds__(256) void spconv_mfma_f32(
    const float* __restrict__ feats,
    const unsigned short* __restrict__ wf,
    const float* __restrict__ bias,
    const int*   __restrict__ in_idx,
    const float* __restrict__ mask,
    float* __restrict__ out, int n)
{
    const int tid  = threadIdx.x;
    const int lane = tid & 63;
    const int wv   = tid >> 6;
    const int rloc = lane & 15;
    const int grp  = lane >> 4;
    const int row0 = blockIdx.x * 128 + wv * 32;

    __shared__ uint4 lds_w[2][512];

    f32x4 acc[2][4];
    #pragma unroll
    for (int nt = 0; nt < 4; ++nt) {
        float b = bias[nt * 16 + rloc];
        f32x4 v = {b, b, b, b};
        acc[0][nt] = v; acc[1][nt] = v;
    }

    const uint4* wf4 = reinterpret_cast<const uint4*>(wf);
    lds_w[0][tid]       = wf4[tid];
    lds_w[0][tid + 256] = wf4[tid + 256];
    __syncthreads();

    const int rowA = row0 + rloc;
    const int rowB = rowA + 16;

    for (int koff = 0; koff < KVOL; ++koff) {
        const int cur = koff & 1;
        uint4 w0, w1;
        const bool pf = (koff + 1 < KVOL);
        if (pf) {
            const uint4* s = wf4 + (size_t)(koff + 1) * 512;
            w0 = s[tid]; w1 = s[tid + 256];
        }

        const size_t kb = (size_t)koff * n;
        const int   idxA = in_idx[kb + rowA];
        const float mA   = mask[kb + rowA];
        const int   idxB = in_idx[kb + rowB];
        const float mB   = mask[kb + rowB];

        const float4* fA = reinterpret_cast<const float4*>(feats + (size_t)idxA * CIN + grp * 8);
        const float4* fB = reinterpret_cast<const float4*>(feats + (size_t)idxB * CIN + grp * 8);
        float4 a0 = fA[0], a1 = fA[1], a2 = fA[8], a3 = fA[9];
        float4 c0 = fB[0], c1 = fB[1], c2 = fB[8], c3 = fB[9];

        bf16x8 aA0 = cvt8(a0, a1, mA), aA1 = cvt8(a2, a3, mA);
        bf16x8 aB0 = cvt8(c0, c1, mB), aB1 = cvt8(c2, c3, mB);

        U4H8 bf[2][4];
        #pragma unroll
        for (int kh = 0; kh < 2; ++kh)
            #pragma unroll
            for (int nt = 0; nt < 4; ++nt)
                bf[kh][nt].u = lds_w[cur][(kh * 4 + nt) * 64 + lane];

        #pragma unroll
        for (int nt = 0; nt < 4; ++nt) {
            acc[0][nt] = __builtin_amdgcn_mfma_f32_16x16x32_bf16(aA0, bf[0][nt].h, acc[0][nt], 0, 0, 0);
            acc[0][nt] = __builtin_amdgcn_mfma_f32_16x16x32_bf16(aA1, bf[1][nt].h, acc[0][nt], 0, 0, 0);
            acc[1][nt] = __builtin_amdgcn_mfma_f32_16x16x32_bf16(aB0, bf[0][nt].h, acc[1][nt], 0, 0, 0);
            acc[1][nt] = __builtin_amdgcn_mfma_f32_16x16x32_bf16(aB1, bf[1][nt].h, acc[1][nt], 0, 0, 0);
        }

        if (pf) {
            lds_w[cur ^ 1][tid]       = w0;
            lds_w[cur ^ 1][tid + 256] = w1;
        }
        __syncthreads();
    }

    #pragma unroll
    for (int t = 0; t < 2; ++t)
        #pragma unroll
        for (int nt = 0; nt < 4; ++nt)
            #pragma unroll
            for (int r = 0; r < 4; ++r) {
                int orow = row0 + t * 16 + grp * 4 + r;
                out[(size_t)orow * COUT + nt * 16 + rloc] = acc[t][nt][r];
            }
}

extern "C" void kernel_launch(void* const* d_in, const int* in_sizes, int n_in,
                              void* d_out, int out_size, void* d_ws, size_t ws_size,
                              hipStream_t stream)
{
    const float* feats  = (const float*)d_in[0];
    const float* weight = (const float*)d_in[1];
    const float* bias   = (const float*)d_in[2];
    const int*   in_idx = (const int*)  d_in[3];
    // d_in[4] = out_idx (unused: out_idx[k][i] == i where mask==1)
    const float* mask   = (const float*)d_in[5];
    float* out = (float*)d_out;

    const int n = in_sizes[0] / CIN;  // 262144

    const size_t WF_BYTES  = (size_t)KVOL * 8 * 64 * 16;          // 221184
    const size_t FBF_BYTES = (size_t)(n + 1) * CIN * 2;           // ~33.6 MB

    unsigned short* wf = (unsigned short*)d_ws;
    const int packN = KVOL * 8 * 64;
    pack_w<<<(packN + 255) / 256, 256, 0, stream>>>(weight, wf);

    if (ws_size >= WF_BYTES + FBF_BYTES) {
        char* fbf = (char*)d_ws + WF_BYTES;
        const int total8 = n * 8;                                  // uint4s of feats
        cvt_feats<<<(total8 + 8 + 255) / 256, 256, 0, stream>>>(feats, (uint4*)fbf, total8);
        spconv_mfma_bf16<<<n / 128, 256, 0, stream>>>(fbf, (const uint4*)wf, bias,
                                                      in_idx, mask, out, n);
    } else {
        spconv_mfma_f32<<<n / 128, 256, 0, stream>>>(feats, wf, bias,
                                                     in_idx, mask, out, n);
    }
}

// Round 4
// 99.125 us; speedup vs baseline: 5.2007x; 1.1281x over previous
//
#include <hip/hip_runtime.h>

#define CIN  64
#define COUT 64
#define KVOL 27

typedef __attribute__((ext_vector_type(8))) short bf16x8;
typedef __attribute__((ext_vector_type(4))) float f32x4;

union U4H8 { uint4 u; bf16x8 h; };

static __device__ __forceinline__ unsigned short f2bf(float x) {
    union { float f; unsigned int u; } v; v.f = x;
    return (unsigned short)((v.u + 0x7FFFu + ((v.u >> 16) & 1u)) >> 16);  // RNE
}

// Re-pack weight[27][64][64] fp32 -> bf16 B-fragment order:
// entry e = (k*8 + frag)*64 + lane holds 8 bf16 = W[k][32*kh + (lane>>4)*8 + j][16*nt + (lane&15)]
__global__ __launch_bounds__(256) void pack_w(const float* __restrict__ W,
                                              unsigned short* __restrict__ wf) {
    int t = blockIdx.x * 256 + threadIdx.x;
    if (t >= KVOL * 8 * 64) return;
    int lane  = t & 63;
    int frag  = (t >> 6) & 7;
    int k     = t >> 9;
    int kh    = frag >> 2, nt = frag & 3;
    int col   = nt * 16 + (lane & 15);
    int kbase = kh * 32 + (lane >> 4) * 8;
    const float* src = W + (size_t)k * (CIN * COUT) + (size_t)kbase * COUT + col;
    unsigned int pk[4];
    #pragma unroll
    for (int j = 0; j < 4; ++j) {
        unsigned int lo = f2bf(src[(2 * j) * COUT]);
        unsigned int hi = f2bf(src[(2 * j + 1) * COUT]);
        pk[j] = lo | (hi << 16);
    }
    *reinterpret_cast<uint4*>(wf + (size_t)t * 8) = make_uint4(pk[0], pk[1], pk[2], pk[3]);
}

// feats fp32 [N][64] -> bf16 [N+1][64] (row N = zeros). One thread = 8 elems.
__global__ __launch_bounds__(256) void cvt_feats(const float* __restrict__ f,
                                                 uint4* __restrict__ o, int total8) {
    int t = blockIdx.x * 256 + threadIdx.x;
    if (t < total8) {
        const float4* p = reinterpret_cast<const float4*>(f) + 2 * (size_t)t;
        float4 a = p[0], b = p[1];
        unsigned int u0 = (unsigned int)f2bf(a.x) | ((unsigned int)f2bf(a.y) << 16);
        unsigned int u1 = (unsigned int)f2bf(a.z) | ((unsigned int)f2bf(a.w) << 16);
        unsigned int u2 = (unsigned int)f2bf(b.x) | ((unsigned int)f2bf(b.y) << 16);
        unsigned int u3 = (unsigned int)f2bf(b.z) | ((unsigned int)f2bf(b.w) << 16);
        o[t] = make_uint4(u0, u1, u2, u3);
    } else if (t < total8 + 8) {
        o[t] = make_uint4(0u, 0u, 0u, 0u);   // zero row at index N
    }
}

// Main: 2 waves/block, 64 rows/wave (4 M-tiles), software-pipelined gathers.
// Dense per-k: invalid pairs gather the zero row (exact zeros).
__global__ __launch_bounds__(128) void spconv_mfma64(
    const char* __restrict__ fbf,          // (n+1) rows x 128 B bf16
    const uint4* __restrict__ wf4,
    const float* __restrict__ bias,
    const int*   __restrict__ in_idx,
    const float* __restrict__ mask,
    float* __restrict__ out, int n)
{
    const int tid  = threadIdx.x;
    const int lane = tid & 63;
    const int wv   = tid >> 6;
    const int rloc = lane & 15;
    const int grp  = lane >> 4;
    const int row0 = blockIdx.x * 128 + wv * 64;

    __shared__ uint4 lds_w[2][512];        // double-buffered B-fragments, 16 KB

    f32x4 acc[4][4];
    #pragma unroll
    for (int nt = 0; nt < 4; ++nt) {
        float b = bias[nt * 16 + rloc];
        f32x4 v = {b, b, b, b};
        acc[0][nt] = v; acc[1][nt] = v; acc[2][nt] = v; acc[3][nt] = v;
    }

    int rowt[4];
    #pragma unroll
    for (int t = 0; t < 4; ++t) rowt[t] = row0 + 16 * t + rloc;

    const unsigned zoff = (unsigned)n * 128u;

    // ---- pipeline prologue ----
    int idxb[4]; float mskb[4];
    #pragma unroll
    for (int t = 0; t < 4; ++t) { idxb[t] = in_idx[rowt[t]]; mskb[t] = mask[rowt[t]]; }

    unsigned offs[2][4];
    #pragma unroll
    for (int t = 0; t < 4; ++t)
        offs[0][t] = (mskb[t] != 0.0f) ? (unsigned)idxb[t] * 128u : zoff;

    #pragma unroll
    for (int t = 0; t < 4; ++t) {               // idx/mask for k=1
        idxb[t] = in_idx[(size_t)n + rowt[t]];
        mskb[t] = mask[(size_t)n + rowt[t]];
    }

    U4H8 a[2][4][2];
    #pragma unroll
    for (int t = 0; t < 4; ++t) {               // A-gathers for k=0
        const uint4* p = reinterpret_cast<const uint4*>(fbf + offs[0][t]) + grp;
        a[0][t][0].u = p[0];
        a[0][t][1].u = p[4];
    }

    lds_w[0][tid]       = wf4[tid];             // stage w(0)
    lds_w[0][tid + 128] = wf4[tid + 128];
    lds_w[0][tid + 256] = wf4[tid + 256];
    lds_w[0][tid + 384] = wf4[tid + 384];
    __syncthreads();

    #pragma unroll
    for (int k = 0; k < KVOL; ++k) {
        const int cur = k & 1;
        const int nxt = cur ^ 1;

        // 1. weight prefetch for k+1 (issued FIRST: ds_write's vmcnt wait
        //    then leaves the younger gathers in flight)
        uint4 w0, w1, w2, w3;
        if (k + 1 < KVOL) {
            const uint4* s = wf4 + (size_t)(k + 1) * 512;
            w0 = s[tid]; w1 = s[tid + 128]; w2 = s[tid + 256]; w3 = s[tid + 384];
        }

        // 2. offsets for k+1 (idx/mask loaded one iter ago)
        if (k + 1 < KVOL) {
            #pragma unroll
            for (int t = 0; t < 4; ++t)
                offs[nxt][t] = (mskb[t] != 0.0f) ? (unsigned)idxb[t] * 128u : zoff;
        }

        // 3. idx/mask for k+2
        if (k + 2 < KVOL) {
            const size_t kb = (size_t)(k + 2) * n;
            #pragma unroll
            for (int t = 0; t < 4; ++t) {
                idxb[t] = in_idx[kb + rowt[t]];
                mskb[t] = mask[kb + rowt[t]];
            }
        }

        // 4. A-gathers for k+1 (land during k's MFMAs / next iter)
        if (k + 1 < KVOL) {
            #pragma unroll
            for (int t = 0; t < 4; ++t) {
                const uint4* p = reinterpret_cast<const uint4*>(fbf + offs[nxt][t]) + grp;
                a[nxt][t][0].u = p[0];
                a[nxt][t][1].u = p[4];
            }
        }

        // 5. B fragments from LDS
        U4H8 bf[2][4];
        #pragma unroll
        for (int kh = 0; kh < 2; ++kh)
            #pragma unroll
            for (int ntl = 0; ntl < 4; ++ntl)
                bf[kh][ntl].u = lds_w[cur][(kh * 4 + ntl) * 64 + lane];

        // 6. 32 MFMAs on fragments gathered last iteration
        #pragma unroll
        for (int t = 0; t < 4; ++t)
            #pragma unroll
            for (int ntl = 0; ntl < 4; ++ntl) {
                acc[t][ntl] = __builtin_amdgcn_mfma_f32_16x16x32_bf16(a[cur][t][0].h, bf[0][ntl].h, acc[t][ntl], 0, 0, 0);
                acc[t][ntl] = __builtin_amdgcn_mfma_f32_16x16x32_bf16(a[cur][t][1].h, bf[1][ntl].h, acc[t][ntl], 0, 0, 0);
            }

        // 7. publish next weight tile
        if (k + 1 < KVOL) {
            lds_w[nxt][tid]       = w0;
            lds_w[nxt][tid + 128] = w1;
            lds_w[nxt][tid + 256] = w2;
            lds_w[nxt][tid + 384] = w3;
            __syncthreads();
        }
    }

    // C/D layout: col = lane&15, row = grp*4 + reg
    #pragma unroll
    for (int t = 0; t < 4; ++t)
        #pragma unroll
        for (int ntl = 0; ntl < 4; ++ntl)
            #pragma unroll
            for (int r = 0; r < 4; ++r) {
                int orow = row0 + 16 * t + grp * 4 + r;
                out[(size_t)orow * COUT + ntl * 16 + rloc] = acc[t][ntl][r];
            }
}

// ---- fallback (round-2 kernel): fp32 gather + in-loop cvt, used if ws too small ----
static __device__ __forceinline__ bf16x8 cvt8(float4 a, float4 b, float m) {
    bf16x8 r;
    r[0] = (short)f2bf(a.x * m); r[1] = (short)f2bf(a.y * m);
    r[2] = (short)f2bf(a.z * m); r[3] = (short)f2bf(a.w * m);
    r[4] = (short)f2bf(b.x * m); r[5] = (short)f2bf(b.y * m);
    r[6] = (short)f2bf(b.z * m); r[7] = (short)f2bf(b.w * m);
    return r;
}

__global__ __launch_bounds__(256) void spconv_mfma_f32(
    const float* __restrict__ feats,
    const unsigned short* __restrict__ wf,
    const float* __restrict__ bias,
    const int*   __restrict__ in_idx,
    const float* __restrict__ mask,
    float* __restrict__ out, int n)
{
    const int tid  = threadIdx.x;
    const int lane = tid & 63;
    const int wv   = tid >> 6;
    const int rloc = lane & 15;
    const int grp  = lane >> 4;
    const int row0 = blockIdx.x * 128 + wv * 32;

    __shared__ uint4 lds_w[2][512];

    f32x4 acc[2][4];
    #pragma unroll
    for (int nt = 0; nt < 4; ++nt) {
        float b = bias[nt * 16 + rloc];
        f32x4 v = {b, b, b, b};
        acc[0][nt] = v; acc[1][nt] = v;
    }

    const uint4* wf4 = reinterpret_cast<const uint4*>(wf);
    lds_w[0][tid]       = wf4[tid];
    lds_w[0][tid + 256] = wf4[tid + 256];
    __syncthreads();

    const int rowA = row0 + rloc;
    const int rowB = rowA + 16;

    for (int koff = 0; koff < KVOL; ++koff) {
        const int cur = koff & 1;
        uint4 w0, w1;
        const bool pf = (koff + 1 < KVOL);
        if (pf) {
            const uint4* s = wf4 + (size_t)(koff + 1) * 512;
            w0 = s[tid]; w1 = s[tid + 256];
        }

        const size_t kb = (size_t)koff * n;
        const int   idxA = in_idx[kb + rowA];
        const float mA   = mask[kb + rowA];
        const int   idxB = in_idx[kb + rowB];
        const float mB   = mask[kb + rowB];

        const float4* fA = reinterpret_cast<const float4*>(feats + (size_t)idxA * CIN + grp * 8);
        const float4* fB = reinterpret_cast<const float4*>(feats + (size_t)idxB * CIN + grp * 8);
        float4 a0 = fA[0], a1 = fA[1], a2 = fA[8], a3 = fA[9];
        float4 c0 = fB[0], c1 = fB[1], c2 = fB[8], c3 = fB[9];

        bf16x8 aA0 = cvt8(a0, a1, mA), aA1 = cvt8(a2, a3, mA);
        bf16x8 aB0 = cvt8(c0, c1, mB), aB1 = cvt8(c2, c3, mB);

        U4H8 bf[2][4];
        #pragma unroll
        for (int kh = 0; kh < 2; ++kh)
            #pragma unroll
            for (int nt = 0; nt < 4; ++nt)
                bf[kh][nt].u = lds_w[cur][(kh * 4 + nt) * 64 + lane];

        #pragma unroll
        for (int nt = 0; nt < 4; ++nt) {
            acc[0][nt] = __builtin_amdgcn_mfma_f32_16x16x32_bf16(aA0, bf[0][nt].h, acc[0][nt], 0, 0, 0);
            acc[0][nt] = __builtin_amdgcn_mfma_f32_16x16x32_bf16(aA1, bf[1][nt].h, acc[0][nt], 0, 0, 0);
            acc[1][nt] = __builtin_amdgcn_mfma_f32_16x16x32_bf16(aB0, bf[0][nt].h, acc[1][nt], 0, 0, 0);
            acc[1][nt] = __builtin_amdgcn_mfma_f32_16x16x32_bf16(aB1, bf[1][nt].h, acc[1][nt], 0, 0, 0);
        }

        if (pf) {
            lds_w[cur ^ 1][tid]       = w0;
            lds_w[cur ^ 1][tid + 256] = w1;
        }
        __syncthreads();
    }

    #pragma unroll
    for (int t = 0; t < 2; ++t)
        #pragma unroll
        for (int nt = 0; nt < 4; ++nt)
            #pragma unroll
            for (int r = 0; r < 4; ++r) {
                int orow = row0 + t * 16 + grp * 4 + r;
                out[(size_t)orow * COUT + nt * 16 + rloc] = acc[t][nt][r];
            }
}

extern "C" void kernel_launch(void* const* d_in, const int* in_sizes, int n_in,
                              void* d_out, int out_size, void* d_ws, size_t ws_size,
                              hipStream_t stream)
{
    const float* feats  = (const float*)d_in[0];
    const float* weight = (const float*)d_in[1];
    const float* bias   = (const float*)d_in[2];
    const int*   in_idx = (const int*)  d_in[3];
    // d_in[4] = out_idx (unused: out_idx[k][i] == i where mask==1)
    const float* mask   = (const float*)d_in[5];
    float* out = (float*)d_out;

    const int n = in_sizes[0] / CIN;  // 262144

    const size_t WF_BYTES  = (size_t)KVOL * 8 * 64 * 16;          // 221184
    const size_t FBF_BYTES = (size_t)(n + 1) * CIN * 2;           // ~33.6 MB

    unsigned short* wf = (unsigned short*)d_ws;
    const int packN = KVOL * 8 * 64;
    pack_w<<<(packN + 255) / 256, 256, 0, stream>>>(weight, wf);

    if (ws_size >= WF_BYTES + FBF_BYTES) {
        char* fbf = (char*)d_ws + WF_BYTES;
        const int total8 = n * 8;                                  // uint4s of feats
        cvt_feats<<<(total8 + 8 + 255) / 256, 256, 0, stream>>>(feats, (uint4*)fbf, total8);
        spconv_mfma64<<<n / 128, 128, 0, stream>>>(fbf, (const uint4*)wf, bias,
                                                   in_idx, mask, out, n);
    } else {
        spconv_mfma_f32<<<n / 128, 256, 0, stream>>>(feats, wf, bias,
                                                     in_idx, mask, out, n);
    }
}